// Round 1
// baseline (1016.075 us; speedup 1.0000x reference)
//
#include <hip/hip_runtime.h>

// Problem constants (match reference setup_inputs)
constexpr int T = 8;
constexpr int R = 200000;
constexpr int D = 128;
constexpr int B = 2048;
constexpr int NUM_BAGS = T * B;              // 16384
constexpr int ROWS = T * R;                  // 1,600,000 total rows
constexpr int ROW_WORDS = D / 4;             // 32 uint words per int8 row (128 B)
constexpr long QW8_BYTES = (long)ROWS * D;   // 204,800,000 B int8 table
constexpr int BM_WORDS = (ROWS + 31) / 32;   // 50,000 bitmap words

typedef int   iv4 __attribute__((ext_vector_type(4)));
typedef float fv2 __attribute__((ext_vector_type(2)));

// ---------- Pass 1: zero the referenced-row bitmap ----------
__global__ __launch_bounds__(256)
void zero_bitmap_kernel(unsigned* __restrict__ bm) {
    int i = blockIdx.x * blockDim.x + threadIdx.x;
    const int stride = gridDim.x * blockDim.x;
    for (; i < BM_WORDS; i += stride) bm[i] = 0u;
}

// ---------- Pass 2: mark rows referenced by any lookup ----------
// One wave per bag; lanes stride the bag's index list (coalesced).
__global__ __launch_bounds__(256)
void mark_rows_kernel(const int* __restrict__ indices,
                      const int* __restrict__ offsets,
                      unsigned* __restrict__ bm) {
    const int wave = (int)((blockIdx.x * blockDim.x + threadIdx.x) >> 6);
    if (wave >= NUM_BAGS) return;
    const int lane = (int)(threadIdx.x & 63);
    const int t = wave >> 11;                 // bag / B (B = 2048)
    const int start = offsets[wave];
    const int end   = offsets[wave + 1];
    const int tbase = t * R;
    for (int j = start + lane; j < end; j += 64) {
        const unsigned row = (unsigned)(tbase + indices[j]);
        atomicOr(&bm[row >> 5], 1u << (row & 31));
    }
}

// ---------- Pass 3: compact referenced int32 rows -> int8 rows ----------
// One half-wave per row (32 lanes x 16B = 512B read, 32 x 4B = 128B write).
// Ascending sparse reads (~28% density) are DRAM-friendly; writes left
// cacheable so the gather pass can hit L2/L3 on the fresh int8 rows.
__global__ __launch_bounds__(256)
void compact_rows_kernel(const int* __restrict__ qweights,
                         const unsigned* __restrict__ bm,
                         unsigned* __restrict__ qw8) {
    const int nwaves = (int)((gridDim.x * blockDim.x) >> 6);
    const int wid    = (int)((blockIdx.x * blockDim.x + threadIdx.x) >> 6);
    const int lane   = (int)(threadIdx.x & 63);
    const int half   = lane >> 5;
    const int sub    = lane & 31;
    const int npairs = ROWS >> 1;
    const iv4* qw4 = (const iv4*)qweights;    // row r -> qw4[r*32 + sub]
    for (int p = wid; p < npairs; p += nwaves) {
        const int row = 2 * p + half;
        if (bm[row >> 5] & (1u << (row & 31))) {
            const iv4 q = __builtin_nontemporal_load(&qw4[(long)row * ROW_WORDS + sub]);
            const unsigned packed =
                  ((unsigned)q.x & 255u)
                | (((unsigned)q.y & 255u) << 8)
                | (((unsigned)q.z & 255u) << 16)
                | (((unsigned)q.w & 255u) << 24);
            qw8[(long)row * ROW_WORDS + sub] = packed;
        }
    }
}

// ---------- Pass 4: gather int8 rows + rowwise dequant + SUM pool ----------
// One wave per bag; two half-waves own alternating lookups. Lane sub loads
// 4B at dim 4*sub -> each row read is one coalesced 32-lane x 4B = 128B
// line (vs 512B before). 8-deep gather batching per half.
__global__ __launch_bounds__(256)
void pool_int8_kernel(const int* __restrict__ indices,
                      const int* __restrict__ offsets,
                      const unsigned* __restrict__ qw8,
                      const float* __restrict__ scale_shift,
                      float* __restrict__ out) {
    const int wave = (int)((blockIdx.x * blockDim.x + threadIdx.x) >> 6);
    if (wave >= NUM_BAGS) return;
    const int lane = (int)(threadIdx.x & 63);
    const int half = lane >> 5;
    const int sub  = lane & 31;

    const int t     = wave >> 11;
    const int batch = wave & (B - 1);

    const int start = offsets[wave];
    const int end   = offsets[wave + 1];
    const int len   = end - start;
    const int C     = len >> 4;               // chunks of 16 lookups

    float acc0 = 0.f, acc1 = 0.f, acc2 = 0.f, acc3 = 0.f;
    float sshift = 0.f;                       // pooled shift, added once

    const int tbase = t * R;
    const fv2* ss2 = (const fv2*)scale_shift; // row r -> ss2[r]

    int idxb[8];
    if (C > 0) {
#pragma unroll
        for (int k = 0; k < 8; ++k) idxb[k] = indices[start + half + 2 * k];
    }

    for (int c = 0; c < C; ++c) {
        unsigned q[8];
        fv2 s[8];
#pragma unroll
        for (int k = 0; k < 8; ++k) {
            const long r = (long)(tbase + idxb[k]);
            q[k] = qw8[r * ROW_WORDS + sub];
            s[k] = ss2[r];
        }
        if (c + 1 < C) {
            const int nbase = start + ((c + 1) << 4) + half;
#pragma unroll
            for (int k = 0; k < 8; ++k) idxb[k] = indices[nbase + 2 * k];
        }
#pragma unroll
        for (int k = 0; k < 8; ++k) {
            const float sc = s[k].x;
            sshift += s[k].y;
            acc0 = fmaf((float)( q[k]        & 255u), sc, acc0);
            acc1 = fmaf((float)((q[k] >>  8) & 255u), sc, acc1);
            acc2 = fmaf((float)((q[k] >> 16) & 255u), sc, acc2);
            acc3 = fmaf((float)( q[k] >> 24        ), sc, acc3);
        }
    }

    // remainder (< 16 lookups), interleaved between halves
    for (int j = start + (C << 4) + half; j < end; j += 2) {
        const long r = (long)(tbase + indices[j]);
        const unsigned q = qw8[r * ROW_WORDS + sub];
        const fv2 ss = ss2[r];
        sshift += ss.y;
        acc0 = fmaf((float)( q        & 255u), ss.x, acc0);
        acc1 = fmaf((float)((q >>  8) & 255u), ss.x, acc1);
        acc2 = fmaf((float)((q >> 16) & 255u), ss.x, acc2);
        acc3 = fmaf((float)( q >> 24        ), ss.x, acc3);
    }

    acc0 += sshift; acc1 += sshift; acc2 += sshift; acc3 += sshift;

    acc0 += __shfl_down(acc0, 32);
    acc1 += __shfl_down(acc1, 32);
    acc2 += __shfl_down(acc2, 32);
    acc3 += __shfl_down(acc3, 32);

    if (half == 0) {
        float4 v = make_float4(acc0, acc1, acc2, acc3);
        ((float4*)(out + (long)batch * (T * D) + t * D))[sub] = v;
    }
}

// ---------- Fallback: previous direct int32-gather kernel ----------
__global__ __launch_bounds__(256)
void qembag_direct_kernel(const int* __restrict__ indices,
                          const int* __restrict__ offsets,
                          const int* __restrict__ qweights,
                          const float* __restrict__ scale_shift,
                          float* __restrict__ out) {
    const int wave_id = (int)((blockIdx.x * blockDim.x + threadIdx.x) >> 6);
    if (wave_id >= NUM_BAGS) return;
    const int lane = (int)(threadIdx.x & 63);
    const int half = lane >> 5;
    const int sub  = lane & 31;

    const int bag   = wave_id;
    const int t     = bag >> 11;
    const int batch = bag & (B - 1);

    const int start = offsets[bag];
    const int end   = offsets[bag + 1];
    const int len   = end - start;
    const int C     = len >> 4;

    float acc0 = 0.f, acc1 = 0.f, acc2 = 0.f, acc3 = 0.f;
    float sshift = 0.f;

    const long tbase = (long)t * R;
    const iv4* qw4 = (const iv4*)qweights;
    const fv2* ss2 = (const fv2*)scale_shift;

    int idxb[8];
    if (C > 0) {
#pragma unroll
        for (int k = 0; k < 8; ++k) idxb[k] = indices[start + half + 2 * k];
    }

    for (int c = 0; c < C; ++c) {
        iv4 q[8];
        fv2 s[8];
#pragma unroll
        for (int k = 0; k < 8; ++k) {
            const long r = tbase + idxb[k];
            q[k] = __builtin_nontemporal_load(&qw4[r * 32 + sub]);
            s[k] = ss2[r];
        }
        if (c + 1 < C) {
            const int nbase = start + ((c + 1) << 4) + half;
#pragma unroll
            for (int k = 0; k < 8; ++k) idxb[k] = indices[nbase + 2 * k];
        }
#pragma unroll
        for (int k = 0; k < 8; ++k) {
            const float sc = s[k].x;
            sshift += s[k].y;
            acc0 = fmaf((float)q[k].x, sc, acc0);
            acc1 = fmaf((float)q[k].y, sc, acc1);
            acc2 = fmaf((float)q[k].z, sc, acc2);
            acc3 = fmaf((float)q[k].w, sc, acc3);
        }
    }

    for (int j = start + (C << 4) + half; j < end; j += 2) {
        const long r = tbase + indices[j];
        const iv4 q = __builtin_nontemporal_load(&qw4[r * 32 + sub]);
        const fv2 ss = ss2[r];
        sshift += ss.y;
        acc0 = fmaf((float)q.x, ss.x, acc0);
        acc1 = fmaf((float)q.y, ss.x, acc1);
        acc2 = fmaf((float)q.z, ss.x, acc2);
        acc3 = fmaf((float)q.w, ss.x, acc3);
    }

    acc0 += sshift; acc1 += sshift; acc2 += sshift; acc3 += sshift;

    acc0 += __shfl_down(acc0, 32);
    acc1 += __shfl_down(acc1, 32);
    acc2 += __shfl_down(acc2, 32);
    acc3 += __shfl_down(acc3, 32);

    if (half == 0) {
        float4 v = make_float4(acc0, acc1, acc2, acc3);
        ((float4*)(out + (long)batch * (T * D) + t * D))[sub] = v;
    }
}

extern "C" void kernel_launch(void* const* d_in, const int* in_sizes, int n_in,
                              void* d_out, int out_size, void* d_ws, size_t ws_size,
                              hipStream_t stream) {
    const int*   indices     = (const int*)d_in[0];
    const int*   offsets     = (const int*)d_in[1];
    const int*   qweights    = (const int*)d_in[2];
    const float* scale_shift = (const float*)d_in[3];
    float*       out         = (float*)d_out;

    const size_t need = (size_t)QW8_BYTES + (size_t)BM_WORDS * 4 + 256;
    if (d_ws != nullptr && ws_size >= need) {
        unsigned* qw8 = (unsigned*)d_ws;
        unsigned* bm  = (unsigned*)((char*)d_ws + QW8_BYTES);  // 205MB, 256B-aligned

        zero_bitmap_kernel<<<64, 256, 0, stream>>>(bm);
        mark_rows_kernel<<<NUM_BAGS / 4, 256, 0, stream>>>(indices, offsets, bm);
        compact_rows_kernel<<<8192, 256, 0, stream>>>(qweights, bm, qw8);
        pool_int8_kernel<<<NUM_BAGS / 4, 256, 0, stream>>>(indices, offsets, qw8,
                                                           scale_shift, out);
    } else {
        qembag_direct_kernel<<<NUM_BAGS / 4, 256, 0, stream>>>(
            indices, offsets, qweights, scale_shift, out);
    }
}

// Round 2
// 932.588 us; speedup vs baseline: 1.0895x; 1.0895x over previous
//
#include <hip/hip_runtime.h>

// Problem constants (match reference setup_inputs)
constexpr int T = 8;
constexpr int R = 200000;
constexpr int D = 128;
constexpr int B = 2048;
constexpr int NUM_BAGS = T * B;  // 16384

typedef int   iv4 __attribute__((ext_vector_type(4)));
typedef float fv2 __attribute__((ext_vector_type(2)));

// One 64-lane wave per bag; two half-waves own alternating lookups.
// Lane sub in a half-wave loads 16B at dim 4*sub -> each row read is one
// coalesced 32-lane x 16B = 512B transaction.
//
// Round-2 change: TRUE software pipeline across chunks. Two register
// buffers (A/B); chunk c+1's 16 gathers are issued BEFORE chunk c is
// consumed, so each wave keeps ~32 row-gathers in flight and the HBM
// round-trip of chunk c+1 hides under the accumulate of chunk c.
// Index loads run one further chunk ahead so gather issue is never
// blocked on an index fetch. Non-temporal hint dropped: ~15% of row
// reads are repeats and the touched set (~230MB) fits the 256MB L3.
__global__ __launch_bounds__(256)
void qembag_kernel(const int* __restrict__ indices,
                   const int* __restrict__ offsets,
                   const int* __restrict__ qweights,
                   const float* __restrict__ scale_shift,
                   float* __restrict__ out) {
    const int wave_id = (int)((blockIdx.x * blockDim.x + threadIdx.x) >> 6);
    if (wave_id >= NUM_BAGS) return;
    const int lane = (int)(threadIdx.x & 63);
    const int half = lane >> 5;   // which lookup of an interleaved pair
    const int sub  = lane & 31;   // 16B chunk within the 512B row

    const int t     = wave_id >> 11;      // bag / B   (B = 2048)
    const int batch = wave_id & (B - 1);  // bag % B

    const int start = offsets[wave_id];
    const int end   = offsets[wave_id + 1];
    const int len   = end - start;
    const int C     = len >> 4;           // full chunks of 16 lookups

    float acc0 = 0.f, acc1 = 0.f, acc2 = 0.f, acc3 = 0.f;
    float sshift = 0.f;                   // pooled shift, added once at end

    const long tbase = (long)t * R;
    const iv4* qw4 = (const iv4*)qweights;    // row r -> qw4[r*32 + sub]
    const fv2* ss2 = (const fv2*)scale_shift; // row r -> ss2[r]

    iv4 qA[8], qB[8];
    fv2 sA[8], sB[8];
    int idxN[8];   // indices of the next chunk to be ISSUED

    if (C > 0) {
        // chunk 0 indices
#pragma unroll
        for (int k = 0; k < 8; ++k) idxN[k] = indices[start + half + 2 * k];
        // issue chunk 0 -> A
#pragma unroll
        for (int k = 0; k < 8; ++k) {
            const long r = tbase + idxN[k];
            qA[k] = qw4[r * 32 + sub];
            sA[k] = ss2[r];
        }
        // prefetch chunk 1 indices
        if (C > 1) {
            const int nb = start + 16 + half;
#pragma unroll
            for (int k = 0; k < 8; ++k) idxN[k] = indices[nb + 2 * k];
        }

        int c = 0;
        for (;;) {
            // issue chunk c+1 -> B; prefetch chunk c+2 indices
            if (c + 1 < C) {
#pragma unroll
                for (int k = 0; k < 8; ++k) {
                    const long r = tbase + idxN[k];
                    qB[k] = qw4[r * 32 + sub];
                    sB[k] = ss2[r];
                }
                if (c + 2 < C) {
                    const int nb = start + ((c + 2) << 4) + half;
#pragma unroll
                    for (int k = 0; k < 8; ++k) idxN[k] = indices[nb + 2 * k];
                }
            }
            // consume chunk c from A
#pragma unroll
            for (int k = 0; k < 8; ++k) {
                const float sc = sA[k].x;
                sshift += sA[k].y;
                acc0 = fmaf((float)qA[k].x, sc, acc0);
                acc1 = fmaf((float)qA[k].y, sc, acc1);
                acc2 = fmaf((float)qA[k].z, sc, acc2);
                acc3 = fmaf((float)qA[k].w, sc, acc3);
            }
            if (++c >= C) break;

            // issue chunk c+1 -> A; prefetch chunk c+2 indices
            if (c + 1 < C) {
#pragma unroll
                for (int k = 0; k < 8; ++k) {
                    const long r = tbase + idxN[k];
                    qA[k] = qw4[r * 32 + sub];
                    sA[k] = ss2[r];
                }
                if (c + 2 < C) {
                    const int nb = start + ((c + 2) << 4) + half;
#pragma unroll
                    for (int k = 0; k < 8; ++k) idxN[k] = indices[nb + 2 * k];
                }
            }
            // consume chunk c from B
#pragma unroll
            for (int k = 0; k < 8; ++k) {
                const float sc = sB[k].x;
                sshift += sB[k].y;
                acc0 = fmaf((float)qB[k].x, sc, acc0);
                acc1 = fmaf((float)qB[k].y, sc, acc1);
                acc2 = fmaf((float)qB[k].z, sc, acc2);
                acc3 = fmaf((float)qB[k].w, sc, acc3);
            }
            if (++c >= C) break;
        }
    }

    // remainder (< 16 lookups), interleaved between halves
    for (int j = start + (C << 4) + half; j < end; j += 2) {
        const long r = tbase + indices[j];
        const iv4 q = qw4[r * 32 + sub];
        const fv2 ss = ss2[r];
        sshift += ss.y;
        acc0 = fmaf((float)q.x, ss.x, acc0);
        acc1 = fmaf((float)q.y, ss.x, acc1);
        acc2 = fmaf((float)q.z, ss.x, acc2);
        acc3 = fmaf((float)q.w, ss.x, acc3);
    }

    acc0 += sshift; acc1 += sshift; acc2 += sshift; acc3 += sshift;

    // Fold the two half-wave partial sums: lane s += lane s+32
    acc0 += __shfl_down(acc0, 32);
    acc1 += __shfl_down(acc1, 32);
    acc2 += __shfl_down(acc2, 32);
    acc3 += __shfl_down(acc3, 32);

    if (half == 0) {
        float4 v = make_float4(acc0, acc1, acc2, acc3);
        ((float4*)(out + (long)batch * (T * D) + t * D))[sub] = v;
    }
}

extern "C" void kernel_launch(void* const* d_in, const int* in_sizes, int n_in,
                              void* d_out, int out_size, void* d_ws, size_t ws_size,
                              hipStream_t stream) {
    const int*   indices     = (const int*)d_in[0];
    const int*   offsets     = (const int*)d_in[1];
    const int*   qweights    = (const int*)d_in[2];
    const float* scale_shift = (const float*)d_in[3];
    float*       out         = (float*)d_out;

    // 4 waves per 256-thread block, one wave per bag
    const int blocks = NUM_BAGS / 4;  // 4096
    qembag_kernel<<<blocks, 256, 0, stream>>>(indices, offsets, qweights,
                                              scale_shift, out);
}